// Round 1
// baseline (106.008 us; speedup 1.0000x reference)
//
#include <hip/hip_runtime.h>
#include <stdint.h>

// W4 group-quantized linear, bf16-MFMA path.
// x[64,4096] f32 -> bf16 (pre-kernel, into d_ws)
// qweight[512,11008] int32 (8 nibbles along K), scales/zeros[32,11008] f32
// out[64,11008] f32 = x @ ((nib - z)*s)
//
// Main kernel: grid (86, 8) blocks of 256 thr. Block tile M64 x N128, K-split 8
// (K=512 per block, chunks of BK=64). Dequant int4->bf16 into LDS each chunk.
// MFMA 16x16x32 bf16 (layouts HW-verified per guide m89/m91).
// LDS row stride 72 ushorts: 16B-aligned b128 + bank-balanced.
// Epilogue: atomicAdd f32 (d_out pre-zeroed with hipMemsetAsync).

#define IN 4096
#define OUT 11008
#define BATCH 64
#define SPLITK 8
#define KSPL (IN / SPLITK) // 512
#define BN 128
#define BK 64
#define NBLK (OUT / BN) // 86
#define LDR 72          // LDS row stride in ushorts (64 data + 8 pad)

typedef __attribute__((ext_vector_type(8))) __bf16 bf16x8;
typedef __attribute__((ext_vector_type(4))) float f32x4;

static __device__ __forceinline__ ushort f2bf(float f) {
  uint32_t u = __float_as_uint(f);
  u += 0x7fff + ((u >> 16) & 1); // RNE
  return (ushort)(u >> 16);
}

__global__ void cvt_x_kernel(const float* __restrict__ x, ushort* __restrict__ xbf) {
  int gid = blockIdx.x * blockDim.x + threadIdx.x; // 65536 threads, 4 elems each
  float4 v = ((const float4*)x)[gid];
  ushort4 o;
  o.x = f2bf(v.x); o.y = f2bf(v.y); o.z = f2bf(v.z); o.w = f2bf(v.w);
  ((ushort4*)xbf)[gid] = o;
}

__global__ __launch_bounds__(256, 2) void mpq_gemm(
    const ushort* __restrict__ xbf,    // [64][4096] bf16
    const int* __restrict__ qweight,   // [512][11008]
    const float* __restrict__ scales,  // [32][11008]
    const float* __restrict__ zeros,   // [32][11008]
    float* __restrict__ out)           // [64][11008]
{
  __shared__ ushort At[64 * LDR];   // A tile: [m][k]
  __shared__ ushort Bt[128 * LDR];  // B tile: [n][k] (transposed for b128 frag reads)

  const int n0 = blockIdx.x * BN;
  const int k0 = blockIdx.y * KSPL;

  const int tid = threadIdx.x;
  const int lane = tid & 63;
  const int w = tid >> 6;
  const int wm = w >> 1, wn = w & 1;
  const int mlane = lane & 15, quad = lane >> 4;

  // A staging: thread -> row rA (0..63), k offset kA (0,16,32,48), 16 ushorts
  const int rA = tid >> 2;
  const int kA = (tid & 3) * 16;
  // B staging: thread -> qweight row rB (0..7), cols ncol + 32*c (c=0..3)
  const int rB = tid >> 5;
  const int ncol = tid & 31;

  f32x4 acc[2][4] = {};

  for (int kc = k0; kc < k0 + KSPL; kc += BK) {
    const int g = kc >> 7; // quant group for this 64-chunk (aligned within group of 128)

    // ---- global loads for this chunk ----
    const uint4* asrc = (const uint4*)(xbf + rA * IN + kc + kA);
    uint4 a0 = asrc[0];
    uint4 a1 = asrc[1];

    int qv[4];
    float sv[4], zv[4];
    const int qrow = (kc >> 3) + rB;
#pragma unroll
    for (int c = 0; c < 4; ++c) {
      int n = ncol + 32 * c;
      qv[c] = qweight[qrow * OUT + n0 + n];
      sv[c] = scales[g * OUT + n0 + n];
      zv[c] = zeros[g * OUT + n0 + n];
    }

    __syncthreads(); // previous chunk's LDS reads done

    // ---- write A tile ----
    *(uint4*)&At[rA * LDR + kA] = a0;
    *(uint4*)&At[rA * LDR + kA + 8] = a1;

    // ---- dequant + write B tile ----
#pragma unroll
    for (int c = 0; c < 4; ++c) {
      const float s = sv[c];
      const float nzs = -zv[c] * s;
      const uint32_t q = (uint32_t)qv[c];
      ushort ob[8];
#pragma unroll
      for (int j = 0; j < 8; ++j) {
        float wf = (float)((q >> (4 * j)) & 0xF);
        ob[j] = f2bf(fmaf(wf, s, nzs));
      }
      *(uint4*)&Bt[(ncol + 32 * c) * LDR + rB * 8] = *(uint4*)ob;
    }

    __syncthreads();

    // ---- MFMA over the chunk: 2 K-steps of 32 ----
#pragma unroll
    for (int ks = 0; ks < BK; ks += 32) {
      bf16x8 af[2], bfr[4];
#pragma unroll
      for (int i = 0; i < 2; ++i)
        af[i] = *(const bf16x8*)&At[(32 * wm + 16 * i + mlane) * LDR + ks + quad * 8];
#pragma unroll
      for (int j = 0; j < 4; ++j)
        bfr[j] = *(const bf16x8*)&Bt[(64 * wn + 16 * j + mlane) * LDR + ks + quad * 8];
#pragma unroll
      for (int i = 0; i < 2; ++i)
#pragma unroll
        for (int j = 0; j < 4; ++j)
          acc[i][j] = __builtin_amdgcn_mfma_f32_16x16x32_bf16(af[i], bfr[j], acc[i][j], 0, 0, 0);
    }
  }

  // ---- epilogue: atomic accumulate across K-splits ----
#pragma unroll
  for (int i = 0; i < 2; ++i) {
    const int mbase = 32 * wm + 16 * i + quad * 4;
#pragma unroll
    for (int j = 0; j < 4; ++j) {
      const int col = n0 + 64 * wn + 16 * j + mlane;
#pragma unroll
      for (int r = 0; r < 4; ++r) {
        atomicAdd(&out[(mbase + r) * OUT + col], acc[i][j][r]);
      }
    }
  }
}

extern "C" void kernel_launch(void* const* d_in, const int* in_sizes, int n_in,
                              void* d_out, int out_size, void* d_ws, size_t ws_size,
                              hipStream_t stream) {
  const float* x = (const float*)d_in[0];
  const int* qweight = (const int*)d_in[1];
  const float* scales = (const float*)d_in[2];
  const float* zeros = (const float*)d_in[3];
  // d_in[4] = g_idx: implicit (i / 128), unused
  float* out = (float*)d_out;
  ushort* xbf = (ushort*)d_ws; // 64*4096*2 = 512 KB

  hipMemsetAsync(d_out, 0, (size_t)BATCH * OUT * sizeof(float), stream);
  cvt_x_kernel<<<256, 256, 0, stream>>>(x, xbf);
  dim3 grid(NBLK, SPLITK);
  mpq_gemm<<<grid, 256, 0, stream>>>(xbf, qweight, scales, zeros, out);
}

// Round 3
// 103.587 us; speedup vs baseline: 1.0234x; 1.0234x over previous
//
#include <hip/hip_runtime.h>
#include <stdint.h>

// W4 group-quantized linear, bf16-MFMA path, v2b: biased-nibble trick.
// (v2 bug: cvt kernel launched with 1/4 the needed threads — xbf was 3/4 poison.)
//
// Key algebra: for quant group g (128 K-values, s,z constant per column):
//   sum_k x*( (nib - z)*s ) = s * [ sum_k x*(128+nib) ] - s*(128+z)*[ sum_k x ]
// MFMA consumes bf16(0x4300|nib) = 128+nib EXACTLY (no cvt/fma/round per nibble);
// per-group rescale folds s,z with 2 fma per acc element. Row sums of the
// *rounded* bf16 x are precomputed so the 128-bias cancels exactly.
//
// Grid (86 N-blocks, 8 K-splits) x 256 thr; tile M64 x N128, K=512/block
// = 4 groups x (2 chunks of BK=64). Epilogue: f32 atomicAdd (out pre-zeroed).

#define IN 4096
#define OUT 11008
#define BATCH 64
#define SPLITK 8
#define KSPL (IN / SPLITK) // 512
#define BN 128
#define BK 64
#define NBLK (OUT / BN) // 86
#define LDR 72          // LDS row stride in ushorts (64 data + 8 pad)

typedef __attribute__((ext_vector_type(8))) __bf16 bf16x8;
typedef __attribute__((ext_vector_type(4))) float f32x4;

static __device__ __forceinline__ ushort f2bf(float f) {
  uint32_t u = __float_as_uint(f);
  u += 0x7fff + ((u >> 16) & 1); // RNE
  return (ushort)(u >> 16);
}
static __device__ __forceinline__ float bf2f(ushort h) {
  return __uint_as_float(((uint32_t)h) << 16);
}

// x f32 -> bf16, plus per-(group,row) sums of the ROUNDED values.
// 65536 threads, 4 elems each; each 32-lane half-wave covers one (row,group) span of 128.
__global__ void cvt_xsum_kernel(const float* __restrict__ x, ushort* __restrict__ xbf,
                                float* __restrict__ xsum) {
  int gid = blockIdx.x * blockDim.x + threadIdx.x;
  float4 v = ((const float4*)x)[gid];
  ushort4 o;
  o.x = f2bf(v.x); o.y = f2bf(v.y); o.z = f2bf(v.z); o.w = f2bf(v.w);
  ((ushort4*)xbf)[gid] = o;
  float s = bf2f(o.x) + bf2f(o.y) + bf2f(o.z) + bf2f(o.w);
#pragma unroll
  for (int m = 1; m <= 16; m <<= 1) s += __shfl_xor(s, m);
  int lane = threadIdx.x & 63;
  if ((lane & 31) == 0) {
    int k4 = gid * 4;
    int m = k4 >> 12;          // row
    int g = (k4 & 4095) >> 7;  // group
    xsum[g * 64 + m] = s;      // [32 groups][64 rows]
  }
}

__global__ __launch_bounds__(256, 3) void mpq_gemm(
    const ushort* __restrict__ xbf,    // [64][4096] bf16
    const int* __restrict__ qweight,   // [512][11008]
    const float* __restrict__ scales,  // [32][11008]
    const float* __restrict__ zeros,   // [32][11008]
    const float* __restrict__ xsum,    // [32][64]
    float* __restrict__ out)           // [64][11008]
{
  __shared__ ushort At[64 * LDR];   // A tile [m][k]
  __shared__ ushort Bt[128 * LDR];  // B tile [n][k] (biased nibbles as bf16)
  __shared__ float xs[4 * 64];      // row sums for this block's 4 groups

  const int n0 = blockIdx.x * BN;
  const int k0 = blockIdx.y * KSPL;
  const int g0 = k0 >> 7;

  const int tid = threadIdx.x;
  const int lane = tid & 63;
  const int w = tid >> 6;
  const int wm = w >> 1, wn = w & 1;
  const int mlane = lane & 15, quad = lane >> 4;

  // stage this block's xsum slice (4 groups x 64 rows)
  xs[tid] = xsum[(g0 + (tid >> 6)) * 64 + (tid & 63)];

  // A staging: row rA (0..63), k offset kA (0,16,32,48), 32 ushorts
  const int rA = tid >> 2;
  const int kA = (tid & 3) * 16;
  // B staging: qweight row rB (0..7) within chunk, cols ncol + 32*c
  const int rB = tid >> 5;
  const int ncol = tid & 31;

  f32x4 macc[2][4] = {};

  for (int gl = 0; gl < 4; ++gl) {
    const int g = g0 + gl;
    // per-group scale/zero for this thread's 4 fragment columns (overlaps MFMA)
    float sj[4], zj[4];
#pragma unroll
    for (int j = 0; j < 4; ++j) {
      const int col = n0 + 64 * wn + 16 * j + mlane;
      sj[j] = scales[g * OUT + col];
      zj[j] = zeros[g * OUT + col];
    }

    f32x4 gacc[2][4] = {};

#pragma unroll
    for (int cc = 0; cc < 2; ++cc) {
      const int kc = k0 + gl * 128 + cc * 64;

      // ---- global loads ----
      const uint4* asrc = (const uint4*)(xbf + rA * IN + kc + kA);
      uint4 a0 = asrc[0];
      uint4 a1 = asrc[1];

      int qv[4];
      const int qrow = (kc >> 3) + rB;
#pragma unroll
      for (int c = 0; c < 4; ++c)
        qv[c] = qweight[qrow * OUT + n0 + ncol + 32 * c];

      __syncthreads(); // previous stage's LDS reads done

      *(uint4*)&At[rA * LDR + kA] = a0;
      *(uint4*)&At[rA * LDR + kA + 8] = a1;

#pragma unroll
      for (int c = 0; c < 4; ++c) {
        const uint32_t q = (uint32_t)qv[c];
        uint32_t p[4];
#pragma unroll
        for (int j = 0; j < 4; ++j) {
          // pair j: nibbles 2j (low16) and 2j+1 (high16), biased: bf16 = 128+nib
          p[j] = 0x43004300u | ((q >> (8 * j)) & 0xFu) | (((q >> (8 * j + 4)) & 0xFu) << 16);
        }
        *(uint4*)&Bt[(ncol + 32 * c) * LDR + rB * 8] = *(uint4*)p;
      }

      __syncthreads();

      // ---- MFMA: 2 K-steps of 32 ----
#pragma unroll
      for (int ks = 0; ks < BK; ks += 32) {
        bf16x8 af[2], bfr[4];
#pragma unroll
        for (int i = 0; i < 2; ++i)
          af[i] = *(const bf16x8*)&At[(32 * wm + 16 * i + mlane) * LDR + ks + quad * 8];
#pragma unroll
        for (int j = 0; j < 4; ++j)
          bfr[j] = *(const bf16x8*)&Bt[(64 * wn + 16 * j + mlane) * LDR + ks + quad * 8];
#pragma unroll
        for (int i = 0; i < 2; ++i)
#pragma unroll
          for (int j = 0; j < 4; ++j)
            gacc[i][j] = __builtin_amdgcn_mfma_f32_16x16x32_bf16(af[i], bfr[j], gacc[i][j], 0, 0, 0);
      }
    }

    // ---- per-group rescale: macc += s*gacc - s*(128+z)*rowsum ----
#pragma unroll
    for (int j = 0; j < 4; ++j) {
      const float uj = sj[j] * (128.0f + zj[j]);
#pragma unroll
      for (int i = 0; i < 2; ++i) {
        const int mbase = 32 * wm + 16 * i + quad * 4;
#pragma unroll
        for (int r = 0; r < 4; ++r) {
          const float S = xs[gl * 64 + mbase + r];
          float acc = macc[i][j][r];
          acc = fmaf(sj[j], gacc[i][j][r], acc);
          acc = fmaf(-uj, S, acc);
          macc[i][j][r] = acc;
        }
      }
    }
  }

  // ---- epilogue: atomic accumulate across K-splits ----
#pragma unroll
  for (int i = 0; i < 2; ++i) {
    const int mbase = 32 * wm + 16 * i + quad * 4;
#pragma unroll
    for (int j = 0; j < 4; ++j) {
      const int col = n0 + 64 * wn + 16 * j + mlane;
#pragma unroll
      for (int r = 0; r < 4; ++r)
        atomicAdd(&out[(mbase + r) * OUT + col], macc[i][j][r]);
    }
  }
}

extern "C" void kernel_launch(void* const* d_in, const int* in_sizes, int n_in,
                              void* d_out, int out_size, void* d_ws, size_t ws_size,
                              hipStream_t stream) {
  const float* x = (const float*)d_in[0];
  const int* qweight = (const int*)d_in[1];
  const float* scales = (const float*)d_in[2];
  const float* zeros = (const float*)d_in[3];
  float* out = (float*)d_out;
  ushort* xbf = (ushort*)d_ws;                        // 512 KB
  float* xsum = (float*)((char*)d_ws + (1 << 19));    // 8 KB

  hipMemsetAsync(d_out, 0, (size_t)BATCH * OUT * sizeof(float), stream);
  cvt_xsum_kernel<<<256, 256, 0, stream>>>(x, xbf, xsum);
  dim3 grid(NBLK, SPLITK);
  mpq_gemm<<<grid, 256, 0, stream>>>(xbf, qweight, scales, zeros, xsum, out);
}